// Round 1
// baseline (210.272 us; speedup 1.0000x reference)
//
#include <hip/hip_runtime.h>
#include <stdint.h>

#define BB 4
#define SS 4096
#define DD 1024
#define FF 4096
#define CAP 512
#define MTOT (BB*CAP)          // 2048
#define NOUT (BB*SS*DD)        // 16777216

typedef unsigned short ushort_t;
typedef float  float4v  __attribute__((ext_vector_type(4)));
typedef short  short8v  __attribute__((ext_vector_type(8)));
typedef unsigned short ushort8v __attribute__((ext_vector_type(8)));
typedef unsigned short ushort4v __attribute__((ext_vector_type(4)));

// ws layout (bytes)
#define OFF_RW   0u             // B*S f32 = 64KB
#define OFF_IDX  (64u*1024u)    // 2048 int = 8KB
#define OFF_WTOP (72u*1024u)    // 2048 f32 = 8KB
#define OFF_ACC  (80u*1024u)    // 4B loss accumulator
#define OFF_A    (1u<<20)       // MTOT*D bf16 = 4MB
#define OFF_W1T  (5u<<20)       // F*D bf16 = 8MB
#define OFF_W2T  (13u<<20)      // D*F bf16 = 8MB
#define OFF_H    (21u<<20)      // MTOT*F bf16 = 16MB (ends 37MB)

__device__ inline ushort_t f2bf(float f) {
  uint32_t u = __builtin_bit_cast(uint32_t, f);
  u = u + 0x7fffu + ((u >> 16) & 1u);
  return (ushort_t)(u >> 16);
}

// ---------------- router: rw = sigmoid(x . w) ----------------
__global__ void router_kernel(const float* __restrict__ x, const float* __restrict__ w,
                              float* __restrict__ rw) {
  int wave = threadIdx.x >> 6;
  int lane = threadIdx.x & 63;
  int row  = blockIdx.x * 4 + wave;            // [0, B*S)
  const float4* xr = (const float4*)(x + (size_t)row * DD);
  const float4* wr = (const float4*)w;
  float s = 0.f;
#pragma unroll
  for (int i = 0; i < 4; i++) {
    float4 a = xr[lane + i * 64];
    float4 b = wr[lane + i * 64];
    s += a.x * b.x + a.y * b.y + a.z * b.z + a.w * b.w;
  }
#pragma unroll
  for (int off = 32; off > 0; off >>= 1) s += __shfl_xor(s, off, 64);
  if (lane == 0) rw[row] = 1.f / (1.f + expf(-s));
}

// ---------------- topk + order + w_top + BCE loss ----------------
__global__ __launch_bounds__(1024) void topk_kernel(const float* __restrict__ rw,
                                                    int* __restrict__ idxs,
                                                    float* __restrict__ wtop,
                                                    float* __restrict__ acc) {
  __shared__ float v[SS];
  __shared__ int   id[SS];
  __shared__ int   seq2[CAP];
  __shared__ int   rank2[CAP];
  __shared__ unsigned char sel[SS];
  __shared__ float wsum[16];
  const int b = blockIdx.x, tid = threadIdx.x;
  const float* rwg = rw + (size_t)b * SS;
  for (int m = tid; m < SS; m += 1024) { v[m] = rwg[m]; id[m] = m; sel[m] = 0; }
  __syncthreads();
  // bitonic sort, final order: value desc, tie -> index asc (matches lax.top_k)
  for (int k = 2; k <= SS; k <<= 1)
    for (int j = k >> 1; j > 0; j >>= 1) {
      for (int t = tid; t < SS / 2; t += 1024) {
        int i = ((t & ~(j - 1)) << 1) | (t & (j - 1));
        int l = i | j;
        float vi = v[i], vl = v[l];
        int ii = id[i], il = id[l];
        bool lbi = (vl > vi) || (vl == vi && il < ii);   // l-elem before i-elem
        bool ibl = (vi > vl) || (vi == vl && ii < il);
        bool sw = ((i & k) == 0) ? lbi : ibl;
        if (sw) { v[i] = vl; v[l] = vi; id[i] = il; id[l] = ii; }
      }
      __syncthreads();
    }
  if (tid < CAP) { int s0 = id[tid]; sel[s0] = 1; seq2[tid] = s0; rank2[tid] = tid; }
  __syncthreads();
  // BCE loss: tgt=1 at selected
  float ls = 0.f;
  for (int m = tid; m < SS; m += 1024) {
    float r = rwg[m];
    float term = sel[m] ? logf(r) : log1pf(-r);
    ls += fmaxf(term, -100.f);
  }
#pragma unroll
  for (int off = 32; off > 0; off >>= 1) ls += __shfl_xor(ls, off, 64);
  if ((tid & 63) == 0) wsum[tid >> 6] = ls;
  __syncthreads();
  if (tid == 0) {
    float t = 0.f;
    for (int i = 0; i < 16; i++) t += wsum[i];
    atomicAdd(acc, t);
  }
  // sort (seq, rank) by seq asc -> idx_sorted, order
  for (int k = 2; k <= CAP; k <<= 1)
    for (int j = k >> 1; j > 0; j >>= 1) {
      __syncthreads();
      if (tid < CAP / 2) {
        int i = ((tid & ~(j - 1)) << 1) | (tid & (j - 1));
        int l = i | j;
        int si = seq2[i], sl = seq2[l];
        bool sw = ((i & k) == 0) ? (sl < si) : (si < sl);
        if (sw) {
          seq2[i] = sl; seq2[l] = si;
          int tr = rank2[i]; rank2[i] = rank2[l]; rank2[l] = tr;
        }
      }
    }
  __syncthreads();
  if (tid < CAP) {
    idxs[b * CAP + tid] = seq2[tid];
    wtop[b * CAP + tid] = rwg[rank2[tid]];   // faithful quirk: rw at position order[c] in [0,cap)
  }
}

__global__ void lossfin_kernel(const float* __restrict__ acc, float* __restrict__ out) {
  out[NOUT] = -acc[0] / (float)(BB * SS);
}

// ---------------- transpose f32 [R][C] -> bf16 [C][R] ----------------
__global__ void transpose_bf16_kernel(const float* __restrict__ in, ushort_t* __restrict__ out,
                                      int R, int C) {
  __shared__ float t[32][33];
  int c0 = blockIdx.x * 32, r0 = blockIdx.y * 32;
#pragma unroll
  for (int i = 0; i < 4; i++) {
    int y = threadIdx.y + i * 8;
    t[y][threadIdx.x] = in[(size_t)(r0 + y) * C + c0 + threadIdx.x];
  }
  __syncthreads();
#pragma unroll
  for (int i = 0; i < 4; i++) {
    int y = threadIdx.y + i * 8;
    out[(size_t)(c0 + y) * R + r0 + threadIdx.x] = f2bf(t[threadIdx.x][y]);
  }
}

// ---------------- gather selected rows of x -> bf16 A ----------------
__global__ void gather_kernel(const float* __restrict__ x, const int* __restrict__ idxs,
                              ushort_t* __restrict__ A) {
  int row = blockIdx.x;                 // [0, MTOT)
  int b = row >> 9;
  int seq = idxs[row];
  const float4* src = (const float4*)(x + ((size_t)(b * SS + seq)) * DD);
  float4 a = src[threadIdx.x];
  ushort4v o;
  o[0] = f2bf(a.x); o[1] = f2bf(a.y); o[2] = f2bf(a.z); o[3] = f2bf(a.w);
  *(ushort4v*)(A + (size_t)row * DD + threadIdx.x * 4) = o;
}

// ---------------- GEMM: C[M][N] = A[M][K] * Bt[N][K]^T, bf16 MFMA ----------------
// MODE 0: epilogue gelu -> Hout bf16 [M][F]
// MODE 1: epilogue *wtop[row], scatter rows to Out at idxs
template <int MODE>
__global__ __launch_bounds__(256) void gemm_kernel(const ushort_t* __restrict__ Ag,
                                                   const ushort_t* __restrict__ Bg, int K,
                                                   ushort_t* __restrict__ Hout,
                                                   float* __restrict__ Out,
                                                   const int* __restrict__ idxs,
                                                   const float* __restrict__ wtop) {
  __shared__ ushort8v lA[1024];   // 128 rows x 64 k, 16B chunks, XOR-swizzled
  __shared__ ushort8v lB[1024];
  __shared__ int   seqL[128];
  __shared__ float wtL[128];
  const int tid = threadIdx.x;
  const int lane = tid & 63, wv = tid >> 6;
  const int wr = wv >> 1, wc = wv & 1;
  const int bm0 = blockIdx.y * 128, bn0 = blockIdx.x * 128;
  if (MODE == 1 && tid < 128) { seqL[tid] = idxs[bm0 + tid]; wtL[tid] = wtop[bm0 + tid]; }
  float4v acc[4][4];
#pragma unroll
  for (int i = 0; i < 4; i++)
#pragma unroll
    for (int j = 0; j < 4; j++) acc[i][j] = (float4v){0.f, 0.f, 0.f, 0.f};

  for (int k0 = 0; k0 < K; k0 += 64) {
    __syncthreads();
#pragma unroll
    for (int it = 0; it < 4; it++) {
      int c = it * 256 + tid;           // chunk idx in [0,1024)
      int r = c >> 3, sl = c & 7;
      lA[c ^ (r & 7)] = *(const ushort8v*)(Ag + (size_t)(bm0 + r) * K + k0 + sl * 8);
      lB[c ^ (r & 7)] = *(const ushort8v*)(Bg + (size_t)(bn0 + r) * K + k0 + sl * 8);
    }
    __syncthreads();
#pragma unroll
    for (int kk = 0; kk < 2; kk++) {
      short8v af[4], bf[4];
      int s = (lane >> 4) + kk * 4;
#pragma unroll
      for (int mi = 0; mi < 4; mi++) {
        int rr = wr * 64 + mi * 16 + (lane & 15);
        af[mi] = __builtin_bit_cast(short8v, lA[rr * 8 + (s ^ (rr & 7))]);
      }
#pragma unroll
      for (int nj = 0; nj < 4; nj++) {
        int rr = wc * 64 + nj * 16 + (lane & 15);
        bf[nj] = __builtin_bit_cast(short8v, lB[rr * 8 + (s ^ (rr & 7))]);
      }
#pragma unroll
      for (int mi = 0; mi < 4; mi++)
#pragma unroll
        for (int nj = 0; nj < 4; nj++)
          acc[mi][nj] = __builtin_amdgcn_mfma_f32_16x16x32_bf16(af[mi], bf[nj], acc[mi][nj], 0, 0, 0);
    }
  }

  if (MODE == 0) {
#pragma unroll
    for (int mi = 0; mi < 4; mi++) {
      int r0 = bm0 + wr * 64 + mi * 16 + ((lane >> 4) << 2);
#pragma unroll
      for (int nj = 0; nj < 4; nj++) {
        int cc = bn0 + wc * 64 + nj * 16 + (lane & 15);
#pragma unroll
        for (int r = 0; r < 4; r++) {
          float xv = acc[mi][nj][r];
          float g = 0.5f * xv * (1.f + tanhf(0.7978845608028654f * (xv + 0.044715f * xv * xv * xv)));
          Hout[(size_t)(r0 + r) * FF + cc] = f2bf(g);
        }
      }
    }
  } else {
#pragma unroll
    for (int mi = 0; mi < 4; mi++) {
      int tr0 = wr * 64 + mi * 16 + ((lane >> 4) << 2);
#pragma unroll
      for (int r = 0; r < 4; r++) {
        int trow = tr0 + r;
        int grow = bm0 + trow;
        int bb2 = grow >> 9;
        int seq = seqL[trow];
        float wt = wtL[trow];
        float* orow = Out + ((size_t)(bb2 * SS + seq)) * DD + bn0 + wc * 64 + (lane & 15);
#pragma unroll
        for (int nj = 0; nj < 4; nj++) orow[nj * 16] = acc[mi][nj][r] * wt;
      }
    }
  }
}

extern "C" void kernel_launch(void* const* d_in, const int* in_sizes, int n_in,
                              void* d_out, int out_size, void* d_ws, size_t ws_size,
                              hipStream_t stream) {
  (void)in_sizes; (void)n_in; (void)out_size; (void)ws_size;
  const float* x  = (const float*)d_in[0];
  const float* wrt = (const float*)d_in[1];
  const float* W1 = (const float*)d_in[2];
  const float* W2 = (const float*)d_in[3];
  float* out = (float*)d_out;
  char* ws = (char*)d_ws;
  float*    rw   = (float*)(ws + OFF_RW);
  int*      idxs = (int*)(ws + OFF_IDX);
  float*    wtop = (float*)(ws + OFF_WTOP);
  float*    acc  = (float*)(ws + OFF_ACC);
  ushort_t* A    = (ushort_t*)(ws + OFF_A);
  ushort_t* W1T  = (ushort_t*)(ws + OFF_W1T);
  ushort_t* W2T  = (ushort_t*)(ws + OFF_W2T);
  ushort_t* H    = (ushort_t*)(ws + OFF_H);

  hipMemsetAsync(d_out, 0, (size_t)NOUT * 4, stream);
  hipMemsetAsync(acc, 0, 4, stream);
  router_kernel<<<dim3(BB * SS / 4), dim3(256), 0, stream>>>(x, wrt, rw);
  topk_kernel<<<dim3(BB), dim3(1024), 0, stream>>>(rw, idxs, wtop, acc);
  lossfin_kernel<<<dim3(1), dim3(1), 0, stream>>>(acc, out);
  transpose_bf16_kernel<<<dim3(FF / 32, DD / 32), dim3(32, 8), 0, stream>>>(W1, W1T, DD, FF);
  transpose_bf16_kernel<<<dim3(DD / 32, FF / 32), dim3(32, 8), 0, stream>>>(W2, W2T, FF, DD);
  gather_kernel<<<dim3(MTOT), dim3(256), 0, stream>>>(x, idxs, A);
  gemm_kernel<0><<<dim3(FF / 128, MTOT / 128), dim3(256), 0, stream>>>(A, W1T, DD, H, nullptr, nullptr, nullptr);
  gemm_kernel<1><<<dim3(DD / 128, MTOT / 128), dim3(256), 0, stream>>>(H, W2T, FF, nullptr, out, idxs, wtop);
}

// Round 2
// 196.676 us; speedup vs baseline: 1.0691x; 1.0691x over previous
//
#include <hip/hip_runtime.h>
#include <stdint.h>

#define BB 4
#define SS 4096
#define DD 1024
#define FF 4096
#define CAP 512
#define MTOT (BB*CAP)          // 2048
#define NOUT (BB*SS*DD)        // 16777216

typedef unsigned short ushort_t;
typedef float  float4v  __attribute__((ext_vector_type(4)));
typedef short  short8v  __attribute__((ext_vector_type(8)));
typedef unsigned short ushort4v __attribute__((ext_vector_type(4)));

// ws layout (bytes)
#define OFF_RW   0u             // B*S f32 = 64KB
#define OFF_IDX  (64u*1024u)    // 2048 int = 8KB
#define OFF_WTOP (72u*1024u)    // 2048 f32 = 8KB
#define OFF_ACC  (80u*1024u)    // 4B loss accumulator
#define OFF_A    (1u<<20)       // MTOT*D bf16 = 4MB
#define OFF_W1T  (5u<<20)       // F*D bf16 = 8MB
#define OFF_W2T  (13u<<20)      // D*F bf16 = 8MB
#define OFF_H    (21u<<20)      // MTOT*F bf16 = 16MB (ends 37MB)

#define GLD16(gsrc, ldst) __builtin_amdgcn_global_load_lds( \
    (const __attribute__((address_space(1))) void*)(gsrc),  \
    (__attribute__((address_space(3))) void*)(ldst), 16, 0, 0)

__device__ inline ushort_t f2bf(float f) {
  uint32_t u = __builtin_bit_cast(uint32_t, f);
  u = u + 0x7fffu + ((u >> 16) & 1u);
  return (ushort_t)(u >> 16);
}

// ---------------- router: rw = sigmoid(x . w) ----------------
__global__ void router_kernel(const float* __restrict__ x, const float* __restrict__ w,
                              float* __restrict__ rw) {
  int wave = threadIdx.x >> 6;
  int lane = threadIdx.x & 63;
  int row  = blockIdx.x * 4 + wave;            // [0, B*S)
  const float4* xr = (const float4*)(x + (size_t)row * DD);
  const float4* wr = (const float4*)w;
  float s = 0.f;
#pragma unroll
  for (int i = 0; i < 4; i++) {
    float4 a = xr[lane + i * 64];
    float4 b = wr[lane + i * 64];
    s += a.x * b.x + a.y * b.y + a.z * b.z + a.w * b.w;
  }
#pragma unroll
  for (int off = 32; off > 0; off >>= 1) s += __shfl_xor(s, off, 64);
  if (lane == 0) rw[row] = 1.f / (1.f + expf(-s));
}

// ---------------- topk + order + w_top + BCE loss ----------------
__global__ __launch_bounds__(1024) void topk_kernel(const float* __restrict__ rw,
                                                    int* __restrict__ idxs,
                                                    float* __restrict__ wtop,
                                                    float* __restrict__ acc) {
  __shared__ float v[SS];
  __shared__ int   id[SS];
  __shared__ int   seq2[CAP];
  __shared__ int   rank2[CAP];
  __shared__ unsigned char sel[SS];
  __shared__ float wsum[16];
  const int b = blockIdx.x, tid = threadIdx.x;
  const float* rwg = rw + (size_t)b * SS;
  for (int m = tid; m < SS; m += 1024) { v[m] = rwg[m]; id[m] = m; sel[m] = 0; }
  __syncthreads();
  // bitonic sort, final order: value desc, tie -> index asc (matches lax.top_k)
  for (int k = 2; k <= SS; k <<= 1)
    for (int j = k >> 1; j > 0; j >>= 1) {
      for (int t = tid; t < SS / 2; t += 1024) {
        int i = ((t & ~(j - 1)) << 1) | (t & (j - 1));
        int l = i | j;
        float vi = v[i], vl = v[l];
        int ii = id[i], il = id[l];
        bool lbi = (vl > vi) || (vl == vi && il < ii);   // l-elem before i-elem
        bool ibl = (vi > vl) || (vi == vl && ii < il);
        bool sw = ((i & k) == 0) ? lbi : ibl;
        if (sw) { v[i] = vl; v[l] = vi; id[i] = il; id[l] = ii; }
      }
      __syncthreads();
    }
  if (tid < CAP) { int s0 = id[tid]; sel[s0] = 1; seq2[tid] = s0; rank2[tid] = tid; }
  __syncthreads();
  // BCE loss: tgt=1 at selected
  float ls = 0.f;
  for (int m = tid; m < SS; m += 1024) {
    float r = rwg[m];
    float term = sel[m] ? logf(r) : log1pf(-r);
    ls += fmaxf(term, -100.f);
  }
#pragma unroll
  for (int off = 32; off > 0; off >>= 1) ls += __shfl_xor(ls, off, 64);
  if ((tid & 63) == 0) wsum[tid >> 6] = ls;
  __syncthreads();
  if (tid == 0) {
    float t = 0.f;
    for (int i = 0; i < 16; i++) t += wsum[i];
    atomicAdd(acc, t);
  }
  // sort (seq, rank) by seq asc -> idx_sorted, order
  for (int k = 2; k <= CAP; k <<= 1)
    for (int j = k >> 1; j > 0; j >>= 1) {
      __syncthreads();
      if (tid < CAP / 2) {
        int i = ((tid & ~(j - 1)) << 1) | (tid & (j - 1));
        int l = i | j;
        int si = seq2[i], sl = seq2[l];
        bool sw = ((i & k) == 0) ? (sl < si) : (si < sl);
        if (sw) {
          seq2[i] = sl; seq2[l] = si;
          int tr = rank2[i]; rank2[i] = rank2[l]; rank2[l] = tr;
        }
      }
    }
  __syncthreads();
  if (tid < CAP) {
    idxs[b * CAP + tid] = seq2[tid];
    wtop[b * CAP + tid] = rwg[rank2[tid]];   // faithful quirk
  }
}

__global__ void lossfin_kernel(const float* __restrict__ acc, float* __restrict__ out) {
  out[NOUT] = -acc[0] / (float)(BB * SS);
}

// ---------------- transpose f32 [R][C] -> bf16 [C][R] ----------------
__global__ void transpose_bf16_kernel(const float* __restrict__ in, ushort_t* __restrict__ out,
                                      int R, int C) {
  __shared__ float t[32][33];
  int c0 = blockIdx.x * 32, r0 = blockIdx.y * 32;
#pragma unroll
  for (int i = 0; i < 4; i++) {
    int y = threadIdx.y + i * 8;
    t[y][threadIdx.x] = in[(size_t)(r0 + y) * C + c0 + threadIdx.x];
  }
  __syncthreads();
#pragma unroll
  for (int i = 0; i < 4; i++) {
    int y = threadIdx.y + i * 8;
    out[(size_t)(c0 + y) * R + r0 + threadIdx.x] = f2bf(t[threadIdx.x][y]);
  }
}

// ---------------- gather selected rows of x -> bf16 A ----------------
__global__ void gather_kernel(const float* __restrict__ x, const int* __restrict__ idxs,
                              ushort_t* __restrict__ A) {
  int row = blockIdx.x;                 // [0, MTOT)
  int b = row >> 9;
  int seq = idxs[row];
  const float4* src = (const float4*)(x + ((size_t)(b * SS + seq)) * DD);
  float4 a = src[threadIdx.x];
  ushort4v o;
  o[0] = f2bf(a.x); o[1] = f2bf(a.y); o[2] = f2bf(a.z); o[3] = f2bf(a.w);
  *(ushort4v*)(A + (size_t)row * DD + threadIdx.x * 4) = o;
}

// ---------------- GEMM m97-structure: C[M][N] = A[M][K] * Bt[N][K]^T ----------------
// 128x128 tile, BK=64, global_load_lds width-16, linear LDS, 2-barrier loop.
// MODE 0: epilogue gelu -> Hout bf16 [M][FF]
// MODE 1: epilogue *wtop[row], scatter rows with atomicAdd (split-K via gridDim.z)
template <int MODE>
__global__ __launch_bounds__(256) void gemm_m97(const ushort_t* __restrict__ Ag,
                                                const ushort_t* __restrict__ Bg, int Kstride,
                                                ushort_t* __restrict__ Hout,
                                                float* __restrict__ Out,
                                                const int* __restrict__ idxs,
                                                const float* __restrict__ wtop) {
  __shared__ ushort_t lA[128 * 64];   // [row][k] linear, 16KB
  __shared__ ushort_t lB[128 * 64];
  __shared__ int   seqL[128];
  __shared__ float wtL[128];
  const int tid = threadIdx.x;
  const int lane = tid & 63, wv = tid >> 6;
  const int wr = wv >> 1, wc = wv & 1;

  // bijective XCD swizzle (nwg % 8 == 0 for both grids: 512, 256)
  const int gx = gridDim.x, gy = gridDim.y;
  const int nwg = gx * gy * gridDim.z;
  int id = blockIdx.x + gx * (blockIdx.y + gy * blockIdx.z);
  int sw = (id & 7) * (nwg >> 3) + (id >> 3);
  const int bx = sw % gx;
  const int by = (sw / gx) % gy;
  const int bz = sw / (gx * gy);

  const int bm0 = by * 128, bn0 = bx * 128;
  const int kchunk = Kstride / gridDim.z;
  const int kbeg = bz * kchunk, kend = kbeg + kchunk;

  if (MODE == 1 && tid < 128) { seqL[tid] = idxs[bm0 + tid]; wtL[tid] = wtop[bm0 + tid]; }

  float4v acc[4][4];
#pragma unroll
  for (int i = 0; i < 4; i++)
#pragma unroll
    for (int j = 0; j < 4; j++) acc[i][j] = (float4v){0.f, 0.f, 0.f, 0.f};

  const int crow = lane >> 3;         // row within an 8-row chunk
  const int ccol = (lane & 7) * 8;    // k-elem offset within row

  for (int k0 = kbeg; k0 < kend; k0 += 64) {
    __syncthreads();
#pragma unroll
    for (int c = 0; c < 4; c++) {
      const int ch = wv * 4 + c;      // chunk 0..15, 8 rows each, 1KB LDS
      const int row = ch * 8 + crow;
      const ushort_t* ga = Ag + (size_t)(bm0 + row) * Kstride + k0 + ccol;
      const ushort_t* gb = Bg + (size_t)(bn0 + row) * Kstride + k0 + ccol;
      GLD16(ga, &lA[ch * 512]);
      GLD16(gb, &lB[ch * 512]);
    }
    __syncthreads();
#pragma unroll
    for (int kk = 0; kk < 2; kk++) {
      const int s = (lane >> 4) + kk * 4;   // 16B k-slot 0..7
      short8v af[4], bfr[4];
#pragma unroll
      for (int mi = 0; mi < 4; mi++)
        af[mi] = *(const short8v*)&lA[(wr * 64 + mi * 16 + (lane & 15)) * 64 + s * 8];
#pragma unroll
      for (int nj = 0; nj < 4; nj++)
        bfr[nj] = *(const short8v*)&lB[(wc * 64 + nj * 16 + (lane & 15)) * 64 + s * 8];
#pragma unroll
      for (int mi = 0; mi < 4; mi++)
#pragma unroll
        for (int nj = 0; nj < 4; nj++)
          acc[mi][nj] = __builtin_amdgcn_mfma_f32_16x16x32_bf16(af[mi], bfr[nj], acc[mi][nj], 0, 0, 0);
    }
  }

  if (MODE == 0) {
#pragma unroll
    for (int mi = 0; mi < 4; mi++) {
      int r0 = bm0 + wr * 64 + mi * 16 + ((lane >> 4) << 2);
#pragma unroll
      for (int nj = 0; nj < 4; nj++) {
        int cc = bn0 + wc * 64 + nj * 16 + (lane & 15);
#pragma unroll
        for (int r = 0; r < 4; r++) {
          float xv = acc[mi][nj][r];
          float g = 0.5f * xv * (1.f + tanhf(0.7978845608028654f * (xv + 0.044715f * xv * xv * xv)));
          Hout[(size_t)(r0 + r) * FF + cc] = f2bf(g);
        }
      }
    }
  } else {
#pragma unroll
    for (int mi = 0; mi < 4; mi++) {
      int tr0 = wr * 64 + mi * 16 + ((lane >> 4) << 2);
#pragma unroll
      for (int r = 0; r < 4; r++) {
        int trow = tr0 + r;
        int grow = bm0 + trow;
        int bb2 = grow >> 9;
        int seq = seqL[trow];
        float wt = wtL[trow];
        float* orow = Out + ((size_t)(bb2 * SS + seq)) * DD + bn0 + wc * 64 + (lane & 15);
#pragma unroll
        for (int nj = 0; nj < 4; nj++) atomicAdd(orow + nj * 16, acc[mi][nj][r] * wt);
      }
    }
  }
}

extern "C" void kernel_launch(void* const* d_in, const int* in_sizes, int n_in,
                              void* d_out, int out_size, void* d_ws, size_t ws_size,
                              hipStream_t stream) {
  (void)in_sizes; (void)n_in; (void)out_size; (void)ws_size;
  const float* x  = (const float*)d_in[0];
  const float* wrt = (const float*)d_in[1];
  const float* W1 = (const float*)d_in[2];
  const float* W2 = (const float*)d_in[3];
  float* out = (float*)d_out;
  char* ws = (char*)d_ws;
  float*    rw   = (float*)(ws + OFF_RW);
  int*      idxs = (int*)(ws + OFF_IDX);
  float*    wtop = (float*)(ws + OFF_WTOP);
  float*    acc  = (float*)(ws + OFF_ACC);
  ushort_t* A    = (ushort_t*)(ws + OFF_A);
  ushort_t* W1T  = (ushort_t*)(ws + OFF_W1T);
  ushort_t* W2T  = (ushort_t*)(ws + OFF_W2T);
  ushort_t* H    = (ushort_t*)(ws + OFF_H);

  hipMemsetAsync(d_out, 0, (size_t)NOUT * 4, stream);
  hipMemsetAsync(acc, 0, 4, stream);
  router_kernel<<<dim3(BB * SS / 4), dim3(256), 0, stream>>>(x, wrt, rw);
  topk_kernel<<<dim3(BB), dim3(1024), 0, stream>>>(rw, idxs, wtop, acc);
  lossfin_kernel<<<dim3(1), dim3(1), 0, stream>>>(acc, out);
  transpose_bf16_kernel<<<dim3(FF / 32, DD / 32), dim3(32, 8), 0, stream>>>(W1, W1T, DD, FF);
  transpose_bf16_kernel<<<dim3(DD / 32, FF / 32), dim3(32, 8), 0, stream>>>(W2, W2T, FF, DD);
  gather_kernel<<<dim3(MTOT), dim3(256), 0, stream>>>(x, idxs, A);
  // GEMM1: [2048x1024] * [4096x1024]^T -> gelu -> H
  gemm_m97<0><<<dim3(FF / 128, MTOT / 128, 1), dim3(256), 0, stream>>>(A, W1T, DD, H, nullptr, nullptr, nullptr);
  // GEMM2: [2048x4096] * [1024x4096]^T -> *wtop -> scatter (split-K=2, atomicAdd)
  gemm_m97<1><<<dim3(DD / 128, MTOT / 128, 2), dim3(256), 0, stream>>>(H, W2T, FF, nullptr, out, idxs, wtop);
}

// Round 3
// 180.878 us; speedup vs baseline: 1.1625x; 1.0873x over previous
//
#include <hip/hip_runtime.h>
#include <stdint.h>

#define BB 4
#define SS 4096
#define DD 1024
#define FF 4096
#define CAP 512
#define MTOT (BB*CAP)          // 2048
#define NOUT (BB*SS*DD)        // 16777216

typedef unsigned short ushort_t;
typedef float  float4v  __attribute__((ext_vector_type(4)));
typedef short  short8v  __attribute__((ext_vector_type(8)));
typedef unsigned short ushort8v __attribute__((ext_vector_type(8)));
typedef unsigned short ushort4v __attribute__((ext_vector_type(4)));

// ws layout (bytes)
#define OFF_RW   0u             // B*S f32 = 64KB
#define OFF_IDX  (64u*1024u)    // 2048 int = 8KB
#define OFF_WTOP (72u*1024u)    // 2048 f32 = 8KB
#define OFF_ACC  (80u*1024u)    // 4B loss accumulator
#define OFF_A    (1u<<20)       // MTOT*D bf16 = 4MB
#define OFF_W1T  (5u<<20)       // F*D bf16 = 8MB
#define OFF_W2T  (13u<<20)      // D*F bf16 = 8MB
#define OFF_H    (21u<<20)      // MTOT*F bf16 = 16MB (ends 37MB)

#define GLD16(gsrc, ldst) __builtin_amdgcn_global_load_lds( \
    (const __attribute__((address_space(1))) void*)(gsrc),  \
    (__attribute__((address_space(3))) void*)(ldst), 16, 0, 0)

__device__ inline ushort_t f2bf(float f) {
  uint32_t u = __builtin_bit_cast(uint32_t, f);
  u = u + 0x7fffu + ((u >> 16) & 1u);
  return (ushort_t)(u >> 16);
}

// ---------------- router: rw = sigmoid(x . w) ----------------
__global__ void router_kernel(const float* __restrict__ x, const float* __restrict__ w,
                              float* __restrict__ rw) {
  int wave = threadIdx.x >> 6;
  int lane = threadIdx.x & 63;
  int row  = blockIdx.x * 4 + wave;            // [0, B*S)
  const float4* xr = (const float4*)(x + (size_t)row * DD);
  const float4* wr = (const float4*)w;
  float s = 0.f;
#pragma unroll
  for (int i = 0; i < 4; i++) {
    float4 a = xr[lane + i * 64];
    float4 b = wr[lane + i * 64];
    s += a.x * b.x + a.y * b.y + a.z * b.z + a.w * b.w;
  }
#pragma unroll
  for (int off = 32; off > 0; off >>= 1) s += __shfl_xor(s, off, 64);
  if (lane == 0) rw[row] = 1.f / (1.f + expf(-s));
}

// ---------------- topk + order + w_top + BCE loss ----------------
__global__ __launch_bounds__(1024) void topk_kernel(const float* __restrict__ rw,
                                                    int* __restrict__ idxs,
                                                    float* __restrict__ wtop,
                                                    float* __restrict__ acc) {
  __shared__ float v[SS];
  __shared__ int   id[SS];
  __shared__ int   seq2[CAP];
  __shared__ int   rank2[CAP];
  __shared__ unsigned char sel[SS];
  __shared__ float wsum[16];
  const int b = blockIdx.x, tid = threadIdx.x;
  const float* rwg = rw + (size_t)b * SS;
  for (int m = tid; m < SS; m += 1024) { v[m] = rwg[m]; id[m] = m; sel[m] = 0; }
  __syncthreads();
  // bitonic sort, final order: value desc, tie -> index asc (matches lax.top_k)
  for (int k = 2; k <= SS; k <<= 1)
    for (int j = k >> 1; j > 0; j >>= 1) {
      for (int t = tid; t < SS / 2; t += 1024) {
        int i = ((t & ~(j - 1)) << 1) | (t & (j - 1));
        int l = i | j;
        float vi = v[i], vl = v[l];
        int ii = id[i], il = id[l];
        bool lbi = (vl > vi) || (vl == vi && il < ii);   // l-elem before i-elem
        bool ibl = (vi > vl) || (vi == vl && ii < il);
        bool sw = ((i & k) == 0) ? lbi : ibl;
        if (sw) { v[i] = vl; v[l] = vi; id[i] = il; id[l] = ii; }
      }
      __syncthreads();
    }
  if (tid < CAP) { int s0 = id[tid]; sel[s0] = 1; seq2[tid] = s0; rank2[tid] = tid; }
  __syncthreads();
  // BCE loss: tgt=1 at selected
  float ls = 0.f;
  for (int m = tid; m < SS; m += 1024) {
    float r = rwg[m];
    float term = sel[m] ? logf(r) : log1pf(-r);
    ls += fmaxf(term, -100.f);
  }
#pragma unroll
  for (int off = 32; off > 0; off >>= 1) ls += __shfl_xor(ls, off, 64);
  if ((tid & 63) == 0) wsum[tid >> 6] = ls;
  __syncthreads();
  if (tid == 0) {
    float t = 0.f;
    for (int i = 0; i < 16; i++) t += wsum[i];
    atomicAdd(acc, t);
  }
  // sort (seq, rank) by seq asc -> idx_sorted, order
  for (int k = 2; k <= CAP; k <<= 1)
    for (int j = k >> 1; j > 0; j >>= 1) {
      __syncthreads();
      if (tid < CAP / 2) {
        int i = ((tid & ~(j - 1)) << 1) | (tid & (j - 1));
        int l = i | j;
        int si = seq2[i], sl = seq2[l];
        bool sw = ((i & k) == 0) ? (sl < si) : (si < sl);
        if (sw) {
          seq2[i] = sl; seq2[l] = si;
          int tr = rank2[i]; rank2[i] = rank2[l]; rank2[l] = tr;
        }
      }
    }
  __syncthreads();
  if (tid < CAP) {
    idxs[b * CAP + tid] = seq2[tid];
    wtop[b * CAP + tid] = rwg[rank2[tid]];   // faithful quirk
  }
}

__global__ void lossfin_kernel(const float* __restrict__ acc, float* __restrict__ out) {
  out[NOUT] = -acc[0] / (float)(BB * SS);
}

// ---------------- transpose f32 [R][C] -> bf16 [C][R] ----------------
__global__ void transpose_bf16_kernel(const float* __restrict__ in, ushort_t* __restrict__ out,
                                      int R, int C) {
  __shared__ float t[32][33];
  int c0 = blockIdx.x * 32, r0 = blockIdx.y * 32;
#pragma unroll
  for (int i = 0; i < 4; i++) {
    int y = threadIdx.y + i * 8;
    t[y][threadIdx.x] = in[(size_t)(r0 + y) * C + c0 + threadIdx.x];
  }
  __syncthreads();
#pragma unroll
  for (int i = 0; i < 4; i++) {
    int y = threadIdx.y + i * 8;
    out[(size_t)(c0 + y) * R + r0 + threadIdx.x] = f2bf(t[threadIdx.x][y]);
  }
}

// ---------------- gather selected rows of x -> bf16 A ----------------
__global__ void gather_kernel(const float* __restrict__ x, const int* __restrict__ idxs,
                              ushort_t* __restrict__ A) {
  int row = blockIdx.x;                 // [0, MTOT)
  int b = row >> 9;
  int seq = idxs[row];
  const float4* src = (const float4*)(x + ((size_t)(b * SS + seq)) * DD);
  float4 a = src[threadIdx.x];
  ushort4v o;
  o[0] = f2bf(a.x); o[1] = f2bf(a.y); o[2] = f2bf(a.z); o[3] = f2bf(a.w);
  *(ushort4v*)(A + (size_t)row * DD + threadIdx.x * 4) = o;
}

// ---------------- GEMM: 128x128 tile, BK=64, double-buffered, counted vmcnt ----------------
// LDS layout: chunk = row*8 + physslot (16B chunks). Physical slot p of row r holds
// global k-slot p ^ (r&7)  (inverse-swizzled SOURCE, linear gld_lds DEST — rule 21).
// MODE 0: epilogue gelu -> Hout bf16 [M][FF]
// MODE 1: epilogue *wtop[row], scatter rows with atomicAdd (split-K via gridDim.z)
template <int MODE>
__global__ __launch_bounds__(256) void gemm_db(const ushort_t* __restrict__ Ag,
                                               const ushort_t* __restrict__ Bg, int Kstride,
                                               ushort_t* __restrict__ Hout,
                                               float* __restrict__ Out,
                                               const int* __restrict__ idxs,
                                               const float* __restrict__ wtop) {
  __shared__ ushort8v lA[2][1024];   // [buf][chunk] 16KB each
  __shared__ ushort8v lB[2][1024];
  __shared__ int   seqL[128];
  __shared__ float wtL[128];
  const int tid = threadIdx.x;
  const int lane = tid & 63, wv = tid >> 6;
  const int wr = wv >> 1, wc = wv & 1;

  // bijective XCD swizzle (nwg % 8 == 0 for both grids: 512, 512)
  const int gx = gridDim.x, gy = gridDim.y;
  const int nwg = gx * gy * gridDim.z;
  int id = blockIdx.x + gx * (blockIdx.y + gy * blockIdx.z);
  int sw = (id & 7) * (nwg >> 3) + (id >> 3);
  const int bx = sw % gx;
  const int by = (sw / gx) % gy;
  const int bz = sw / (gx * gy);

  const int bm0 = by * 128, bn0 = bx * 128;
  const int kchunk = Kstride / gridDim.z;
  const int kbeg = bz * kchunk;
  const int nsteps = kchunk / 64;

  if (MODE == 1 && tid < 128) { seqL[tid] = idxs[bm0 + tid]; wtL[tid] = wtop[bm0 + tid]; }

  // staging geometry: call c, wave wv, lane l -> chunk = c*256 + wv*64 + l
  // row = c*32 + wv*8 + (l>>3), physslot = l&7, global slot = (l&7) ^ (l>>3)
  const int srow_off = lane >> 3;
  const int gslot = (lane & 7) ^ (lane >> 3);

  float4v acc[4][4];
#pragma unroll
  for (int i = 0; i < 4; i++)
#pragma unroll
    for (int j = 0; j < 4; j++) acc[i][j] = (float4v){0.f, 0.f, 0.f, 0.f};

#define STAGE(buf, k0)                                                          \
  {                                                                             \
    _Pragma("unroll")                                                           \
    for (int c = 0; c < 4; c++) {                                               \
      const int chunkbase = c * 256 + wv * 64;        /* wave-uniform */        \
      const int row = c * 32 + wv * 8 + srow_off;                               \
      const ushort_t* ga = Ag + (size_t)(bm0 + row) * Kstride + (k0) + gslot * 8; \
      const ushort_t* gb = Bg + (size_t)(bn0 + row) * Kstride + (k0) + gslot * 8; \
      GLD16(ga, &lA[buf][chunkbase]);                                           \
      GLD16(gb, &lB[buf][chunkbase]);                                           \
    }                                                                           \
  }

  STAGE(0, kbeg);
  int cur = 0;
  for (int t = 0; t < nsteps; ++t) {
    if (t + 1 < nsteps) {
      STAGE(cur ^ 1, kbeg + (t + 1) * 64);
      asm volatile("s_waitcnt vmcnt(8)" ::: "memory");   // oldest 8 (= buf[cur]) landed
    } else {
      asm volatile("s_waitcnt vmcnt(0)" ::: "memory");
    }
    __builtin_amdgcn_s_barrier();
    __builtin_amdgcn_sched_barrier(0);
    __builtin_amdgcn_s_setprio(1);
#pragma unroll
    for (int kk = 0; kk < 2; kk++) {
      const int s = (lane >> 4) + kk * 4;   // logical 16B k-slot 0..7
      short8v af[4], bfr[4];
#pragma unroll
      for (int mi = 0; mi < 4; mi++) {
        const int rr = wr * 64 + mi * 16 + (lane & 15);
        af[mi] = __builtin_bit_cast(short8v, lA[cur][rr * 8 + (s ^ (rr & 7))]);
      }
#pragma unroll
      for (int nj = 0; nj < 4; nj++) {
        const int rr = wc * 64 + nj * 16 + (lane & 15);
        bfr[nj] = __builtin_bit_cast(short8v, lB[cur][rr * 8 + (s ^ (rr & 7))]);
      }
#pragma unroll
      for (int mi = 0; mi < 4; mi++)
#pragma unroll
        for (int nj = 0; nj < 4; nj++)
          acc[mi][nj] = __builtin_amdgcn_mfma_f32_16x16x32_bf16(af[mi], bfr[nj], acc[mi][nj], 0, 0, 0);
    }
    __builtin_amdgcn_s_setprio(0);
    __builtin_amdgcn_sched_barrier(0);
    __builtin_amdgcn_s_barrier();     // buf[cur] reads done chip-wide; safe to overwrite next iter
    cur ^= 1;
  }
#undef STAGE

  if (MODE == 0) {
#pragma unroll
    for (int mi = 0; mi < 4; mi++) {
      int r0 = bm0 + wr * 64 + mi * 16 + ((lane >> 4) << 2);
#pragma unroll
      for (int nj = 0; nj < 4; nj++) {
        int cc = bn0 + wc * 64 + nj * 16 + (lane & 15);
#pragma unroll
        for (int r = 0; r < 4; r++) {
          float xv = acc[mi][nj][r];
          float g = 0.5f * xv * (1.f + tanhf(0.7978845608028654f * (xv + 0.044715f * xv * xv * xv)));
          Hout[(size_t)(r0 + r) * FF + cc] = f2bf(g);
        }
      }
    }
  } else {
#pragma unroll
    for (int mi = 0; mi < 4; mi++) {
      int tr0 = wr * 64 + mi * 16 + ((lane >> 4) << 2);
#pragma unroll
      for (int r = 0; r < 4; r++) {
        int trow = tr0 + r;
        int grow = bm0 + trow;
        int bb2 = grow >> 9;
        int seq = seqL[trow];
        float wt = wtL[trow];
        float* orow = Out + ((size_t)(bb2 * SS + seq)) * DD + bn0 + wc * 64 + (lane & 15);
#pragma unroll
        for (int nj = 0; nj < 4; nj++) atomicAdd(orow + nj * 16, acc[mi][nj][r] * wt);
      }
    }
  }
}

extern "C" void kernel_launch(void* const* d_in, const int* in_sizes, int n_in,
                              void* d_out, int out_size, void* d_ws, size_t ws_size,
                              hipStream_t stream) {
  (void)in_sizes; (void)n_in; (void)out_size; (void)ws_size;
  const float* x  = (const float*)d_in[0];
  const float* wrt = (const float*)d_in[1];
  const float* W1 = (const float*)d_in[2];
  const float* W2 = (const float*)d_in[3];
  float* out = (float*)d_out;
  char* ws = (char*)d_ws;
  float*    rw   = (float*)(ws + OFF_RW);
  int*      idxs = (int*)(ws + OFF_IDX);
  float*    wtop = (float*)(ws + OFF_WTOP);
  float*    acc  = (float*)(ws + OFF_ACC);
  ushort_t* A    = (ushort_t*)(ws + OFF_A);
  ushort_t* W1T  = (ushort_t*)(ws + OFF_W1T);
  ushort_t* W2T  = (ushort_t*)(ws + OFF_W2T);
  ushort_t* H    = (ushort_t*)(ws + OFF_H);

  hipMemsetAsync(d_out, 0, (size_t)NOUT * 4, stream);
  hipMemsetAsync(acc, 0, 4, stream);
  router_kernel<<<dim3(BB * SS / 4), dim3(256), 0, stream>>>(x, wrt, rw);
  topk_kernel<<<dim3(BB), dim3(1024), 0, stream>>>(rw, idxs, wtop, acc);
  lossfin_kernel<<<dim3(1), dim3(1), 0, stream>>>(acc, out);
  transpose_bf16_kernel<<<dim3(FF / 32, DD / 32), dim3(32, 8), 0, stream>>>(W1, W1T, DD, FF);
  transpose_bf16_kernel<<<dim3(DD / 32, FF / 32), dim3(32, 8), 0, stream>>>(W2, W2T, FF, DD);
  gather_kernel<<<dim3(MTOT), dim3(256), 0, stream>>>(x, idxs, A);
  // GEMM1: [2048x1024] * [4096x1024]^T -> gelu -> H   (512 blocks = 2/CU, LDS-cap matched)
  gemm_db<0><<<dim3(FF / 128, MTOT / 128, 1), dim3(256), 0, stream>>>(A, W1T, DD, H, nullptr, nullptr, nullptr);
  // GEMM2: [2048x4096] * [1024x4096]^T -> *wtop -> scatter (split-K=4, atomicAdd)
  gemm_db<1><<<dim3(DD / 128, MTOT / 128, 4), dim3(256), 0, stream>>>(H, W2T, FF, nullptr, out, idxs, wtop);
}